// Round 11
// baseline (200.090 us; speedup 1.0000x reference)
//
#include <hip/hip_runtime.h>
#include <hip/hip_bf16.h>

typedef float f32x4 __attribute__((ext_vector_type(4)));
typedef short s16x8 __attribute__((ext_vector_type(8)));
typedef unsigned short u16x4 __attribute__((ext_vector_type(4)));
typedef unsigned short u16x8 __attribute__((ext_vector_type(8)));

#define MFMA16(a,b,c) __builtin_amdgcn_mfma_f32_16x16x32_bf16(a,b,c,0,0,0)

#define NTOK 3136
#define NKV  784
#define NKVP 800
#define CD   256
#define NH   8
#define HD   32
#define PEW  111
#define LOG2E 1.4426950408889634f
#define SC2  (0.17677669529663687f * 1.4426950408889634f)

static __device__ __forceinline__ unsigned short f2b(float f){
  unsigned int u = __float_as_uint(f);
  return (unsigned short)((u + 0x7fffu + ((u>>16)&1u)) >> 16);
}
static __device__ __forceinline__ float b2f(unsigned short u){
  return __uint_as_float(((unsigned int)u)<<16);
}
static __device__ __forceinline__ void gload16(const unsigned short* g, unsigned short* l){
  __builtin_amdgcn_global_load_lds(
      (const __attribute__((address_space(1))) unsigned int*)g,
      (__attribute__((address_space(3))) unsigned int*)l, 16, 0, 0);
}
// fast bf16 pack of 8 positive floats (round-half-up; ties differ from RNE only)
static __device__ __forceinline__ s16x8 pack8(const float* p){
  union { uint4 u; s16x8 s; } w;
  unsigned int a0=__float_as_uint(p[0])+0x8000u, a1=__float_as_uint(p[1])+0x8000u;
  unsigned int a2=__float_as_uint(p[2])+0x8000u, a3=__float_as_uint(p[3])+0x8000u;
  unsigned int a4=__float_as_uint(p[4])+0x8000u, a5=__float_as_uint(p[5])+0x8000u;
  unsigned int a6=__float_as_uint(p[6])+0x8000u, a7=__float_as_uint(p[7])+0x8000u;
  w.u.x = (a0>>16) | (a1 & 0xFFFF0000u);
  w.u.y = (a2>>16) | (a3 & 0xFFFF0000u);
  w.u.z = (a4>>16) | (a5 & 0xFFFF0000u);
  w.u.w = (a6>>16) | (a7 & 0xFFFF0000u);
  return w.s;
}

// ---- fused prep:
// [0,64)      coalesced LDS-tile transposes: 0-15 Wq, 16-31 pw, 32-63 Wkv
// [64,1088)   srwb2 reorder
// [1088,1216) K/V pad zero
// [1216,4352) bias table
// [4352,5136) x transpose+cvt
__global__ __launch_bounds__(256) void k_prep(
      const float* __restrict__ Wq, const float* __restrict__ Wkv,
      const float* __restrict__ pw, const float* __restrict__ srw,
      const float* __restrict__ pos, const float* __restrict__ x,
      unsigned short* __restrict__ WqT, unsigned short* __restrict__ WkvT,
      unsigned short* __restrict__ pwT, unsigned short* __restrict__ srwb2,
      unsigned short* __restrict__ bias2, unsigned short* __restrict__ xbf,
      unsigned short* __restrict__ kb, unsigned short* __restrict__ vT){
  __shared__ float tile[64][65];
  const int blk = blockIdx.x, t = threadIdx.x;
  const int tx = t&15, ty = t>>4;
  if (blk < 64){
    const float* src; unsigned short* dst; int sr0, sc0, sstr;
    if (blk < 16){ src=Wq; dst=WqT; sstr=256; sr0=(blk>>2)*64; sc0=(blk&3)*64; }
    else if (blk < 32){ int b2=blk-16; src=pw; dst=pwT; sstr=256; sr0=(b2>>2)*64; sc0=(b2&3)*64; }
    else { int b2=blk-32; src=Wkv; dst=WkvT; sstr=512; sr0=(b2>>3)*64; sc0=(b2&7)*64; }
#pragma unroll
    for (int j=0;j<4;++j){
      f32x4 v = *(const f32x4*)&src[(size_t)(sr0+ty+j*16)*sstr + sc0 + tx*4];
      tile[ty+j*16][tx*4+0]=v[0]; tile[ty+j*16][tx*4+1]=v[1];
      tile[ty+j*16][tx*4+2]=v[2]; tile[ty+j*16][tx*4+3]=v[3];
    }
    __syncthreads();
    const int nr = t>>2, ccb = (t&3)*16;
    u16x8 o0, o1;
#pragma unroll
    for (int u=0;u<8;++u){ o0[u]=f2b(tile[ccb+u][nr]); o1[u]=f2b(tile[ccb+8+u][nr]); }
    unsigned short* dp = &dst[(size_t)(sc0+nr)*256 + sr0 + ccb];
    *(u16x8*)dp = o0;
    *(u16x8*)(dp+8) = o1;
  } else if (blk < 1088){
    int j = (blk-64)*256 + t;                  // 262144
    int o=j>>10, rem=j&1023, khw=rem>>8, ci=rem&255;
    srwb2[j] = f2b(srw[o*1024 + ci*4 + khw]);
  } else if (blk < 1216){
    int i = (blk-1088)*256 + t;                // 32768
    if (i < 16384){
      int bh=i>>9, r=i&511, ridx=r>>5, d=r&31;
      int row = 776 + (ridx&7) + (ridx>>3)*16; // permuted pad rows
      kb[((size_t)bh*NKVP + row)*HD + d] = 0;
    } else {
      int j=i-16384;
      int bh=j>>9, r=j&511, d=r>>4, key=784+(r&15);
      vT[((size_t)bh*HD + d)*NKVP + key] = 0;
    }
  } else if (blk < 4352){
    int n = blk - 1216;
    if (t < 200){
      int nr2 = (n*9363)>>19, nc = n - nr2*56;
      u16x4 o;
#pragma unroll
      for (int j=0;j<4;++j){
        int key = t*4 + j;
        float v;
        if (key < NKV){
          int tt = (key*9363)>>19, mm = key - tt*56;
          v = pos[(tt-nr2+55)*PEW + (mm-nc+55)] * LOG2E;
        } else v = -100000.f;
        o[j] = f2b(v);
      }
      *(u16x4*)&bias2[(size_t)n*NKVP + t*4] = o;
    }
  } else {
    int bx = blk - 4352;
    const int n0 = (bx%49)*64; int c4 = bx/49;
    const int c0 = (c4&3)*64, b = c4>>2;
#pragma unroll
    for (int j=0;j<4;++j){
      f32x4 v = *(const f32x4*)&x[(size_t)(b*CD + c0+ty+j*16)*NTOK + n0 + tx*4];
      tile[ty+j*16][tx*4+0]=v[0]; tile[ty+j*16][tx*4+1]=v[1];
      tile[ty+j*16][tx*4+2]=v[2]; tile[ty+j*16][tx*4+3]=v[3];
    }
    __syncthreads();
    const int nr = t>>2, ccb = (t&3)*16;
    u16x8 o0, o1;
#pragma unroll
    for (int u=0;u<8;++u){ o0[u]=f2b(tile[ccb+u][nr]); o1[u]=f2b(tile[ccb+8+u][nr]); }
    unsigned short* dst = &xbf[((size_t)b*NTOK + n0+nr)*CD + c0 + ccb];
    *(u16x8*)dst = o0;
    *(u16x8*)(dst+8) = o1;
  }
}

// ---- fused qproj (blocks 0..783) + conv (blocks 784..979)
__global__ __launch_bounds__(256) void k_qc(const unsigned short* __restrict__ xbf,
      const unsigned short* __restrict__ WqT, const unsigned short* __restrict__ srwb2,
      const float* __restrict__ srb, unsigned short* __restrict__ qb,
      float* __restrict__ convo){
  const int gid = blockIdx.x;
  const int tid=threadIdx.x, wv=tid>>6, l=tid&63, g=l>>4, ln16=l&15;
  if (gid < 784){
    // ---------------- q projection ----------------
    const int bx = gid % 196, by = gid / 196;
    const int bI = bx/49;
    const int n0 = (bx%49)*64;
    const int m0 = n0 + (wv>>1)*32;
    const int c0 = by*64 + (wv&1)*32;
    const unsigned short* ap0 = &xbf[((size_t)bI*NTOK + m0+ln16)*CD + g*8];
    const unsigned short* ap1 = ap0 + 16*CD;
    const unsigned short* bp0 = &WqT[(size_t)(c0+ln16)*CD + g*8];
    const unsigned short* bp1 = bp0 + 16*CD;
    f32x4 acc[2][2] = {};
    s16x8 a0 = *(const s16x8*)ap0, a1 = *(const s16x8*)ap1;
    s16x8 w0 = *(const s16x8*)bp0, w1 = *(const s16x8*)bp1;
#pragma unroll
    for (int k0=0; k0<CD; k0+=32){
      s16x8 na0 = *(const s16x8*)(ap0 + k0+32);
      s16x8 na1 = *(const s16x8*)(ap1 + k0+32);
      s16x8 nw0 = *(const s16x8*)(bp0 + k0+32);
      s16x8 nw1 = *(const s16x8*)(bp1 + k0+32);
      acc[0][0] = MFMA16(a0, w0, acc[0][0]);
      acc[0][1] = MFMA16(a0, w1, acc[0][1]);
      acc[1][0] = MFMA16(a1, w0, acc[1][0]);
      acc[1][1] = MFMA16(a1, w1, acc[1][1]);
      a0=na0; a1=na1; w0=nw0; w1=nw1;
    }
#pragma unroll
    for (int mi=0;mi<2;++mi)
#pragma unroll
      for (int ni=0;ni<2;++ni){
        int c = c0 + ni*16 + ln16;
#pragma unroll
        for (int r=0;r<4;++r){
          int n = m0 + mi*16 + g*4 + r;
          qb[((size_t)bI*NTOK + n)*CD + c] = f2b(acc[mi][ni][r] * SC2);
        }
      }
  } else {
    // ---------------- conv as GEMM ----------------
    const int cid = gid - 784;
    const int m0 = (cid%49)*64 + (wv>>1)*32;
    const int c0 = (cid/49)*64 + (wv&1)*32;
    size_t abase[2][4];
#pragma unroll
    for (int mi=0;mi<2;++mi){
      int m = m0 + mi*16 + ln16;
      int bb = (m>=2352)?3:(m>=1568)?2:(m>=784)?1:0;
      int nk = m - bb*784;
      int pp = (nk*9363)>>18, qq = nk - pp*28;
#pragma unroll
      for (int khw=0;khw<4;++khw){
        int kh = khw>>1, kw = khw&1;
        abase[mi][khw] = ((size_t)bb*NTOK + (2*pp+kh)*56 + 2*qq+kw)*CD;
      }
    }
    const unsigned short* wp0 = &srwb2[(size_t)(c0+ln16)*1024 + g*8];
    const unsigned short* wp1 = wp0 + 16*1024;
    f32x4 acc[2][2] = {};
    s16x8 a0 = *(const s16x8*)&xbf[abase[0][0] + g*8];
    s16x8 a1 = *(const s16x8*)&xbf[abase[1][0] + g*8];
    s16x8 w0 = *(const s16x8*)wp0;
    s16x8 w1 = *(const s16x8*)wp1;
#pragma unroll
    for (int s=0; s<32; ++s){
      const int s1 = s+1;
      const int khw2 = (s1>>3)&3, kc2 = (s1&7)*32;
      const int woff = (s1&31)*32;
      s16x8 na0 = *(const s16x8*)&xbf[abase[0][khw2] + kc2 + g*8];
      s16x8 na1 = *(const s16x8*)&xbf[abase[1][khw2] + kc2 + g*8];
      s16x8 nw0 = *(const s16x8*)(wp0 + woff);
      s16x8 nw1 = *(const s16x8*)(wp1 + woff);
      acc[0][0] = MFMA16(a0, w0, acc[0][0]);
      acc[0][1] = MFMA16(a0, w1, acc[0][1]);
      acc[1][0] = MFMA16(a1, w0, acc[1][0]);
      acc[1][1] = MFMA16(a1, w1, acc[1][1]);
      a0=na0; a1=na1; w0=nw0; w1=nw1;
    }
#pragma unroll
    for (int mi=0;mi<2;++mi)
#pragma unroll
      for (int ni=0;ni<2;++ni){
        int c = c0 + ni*16 + ln16;
        float bias = srb[c];
#pragma unroll
        for (int r=0;r<4;++r){
          int m = m0 + mi*16 + g*4 + r;
          convo[(size_t)m*CD + c] = acc[mi][ni][r] + bias;
        }
      }
  }
}

// ---- fused LayerNorm + kv projection + scatter. grid (49,8)
__global__ __launch_bounds__(256) void k_kvln(const float* __restrict__ co,
      const float* __restrict__ gam, const float* __restrict__ bet,
      const unsigned short* __restrict__ WkvT, unsigned short* __restrict__ kb,
      unsigned short* __restrict__ vT){
  __shared__ unsigned short As[64*256];   // 32 KB, 16B-slot swizzled rows
  const int tid=threadIdx.x, wv=tid>>6, l=tid&63, g=l>>4, ln16=l&15;
  const int m0blk = blockIdx.x*64;
  { // LN phase: thread -> row rl = tid>>2, cols cs..cs+63
    const int rl = tid>>2, cs = (tid&3)*64;
    const float* src = &co[(size_t)(m0blk+rl)*CD + cs];
    f32x4 vals[16];
    float s=0.f, s2=0.f;
#pragma unroll
    for (int i=0;i<16;++i){
      vals[i] = *(const f32x4*)(src + i*4);
#pragma unroll
      for (int q=0;q<4;++q){ s += vals[i][q]; s2 += vals[i][q]*vals[i][q]; }
    }
    s += __shfl_xor(s,1); s2 += __shfl_xor(s2,1);
    s += __shfl_xor(s,2); s2 += __shfl_xor(s2,2);
    float mu = s*(1.f/CD);
    float rs = rsqrtf(s2*(1.f/CD) - mu*mu + 1e-5f);
#pragma unroll
    for (int u=0;u<8;++u){
      f32x4 g4a = *(const f32x4*)&gam[cs+u*8];
      f32x4 g4b = *(const f32x4*)&gam[cs+u*8+4];
      f32x4 b4a = *(const f32x4*)&bet[cs+u*8];
      f32x4 b4b = *(const f32x4*)&bet[cs+u*8+4];
      u16x8 o;
#pragma unroll
      for (int q=0;q<4;++q){
        o[q]   = f2b((vals[u*2][q]  -mu)*rs*g4a[q] + b4a[q]);
        o[4+q] = f2b((vals[u*2+1][q]-mu)*rs*g4b[q] + b4b[q]);
      }
      int off = (rl*256 + cs + u*8) ^ ((rl&7)<<3);   // ushort units; 16B slot swizzle
      *(u16x8*)&As[off] = o;
    }
  }
  __syncthreads();
  // GEMM phase: A from LDS (swizzled), B from global (register pipelined)
  const int mw0 = (wv>>1)*32;
  const int c0 = blockIdx.y*64 + (wv&1)*32;
  const unsigned short* bp0 = &WkvT[(size_t)(c0+ln16)*CD + g*8];
  const unsigned short* bp1 = bp0 + 16*CD;
  f32x4 acc[2][2] = {};
  s16x8 w0 = *(const s16x8*)bp0, w1 = *(const s16x8*)bp1;
  const int mr0 = mw0 + ln16, mr1 = mw0 + 16 + ln16;
#pragma unroll
  for (int k0=0; k0<CD; k0+=32){
    s16x8 a0 = *(const s16x8*)&As[(mr0*256 + k0 + g*8) ^ ((mr0&7)<<3)];
    s16x8 a1 = *(const s16x8*)&As[(mr1*256 + k0 + g*8) ^ ((mr1&7)<<3)];
    s16x8 nw0 = w0, nw1 = w1;
    if (k0 < CD-32){
      nw0 = *(const s16x8*)(bp0 + k0+32);
      nw1 = *(const s16x8*)(bp1 + k0+32);
    }
    acc[0][0] = MFMA16(a0, w0, acc[0][0]);
    acc[0][1] = MFMA16(a0, w1, acc[0][1]);
    acc[1][0] = MFMA16(a1, w0, acc[1][0]);
    acc[1][1] = MFMA16(a1, w1, acc[1][1]);
    w0=nw0; w1=nw1;
  }
#pragma unroll
  for (int mi=0;mi<2;++mi)
#pragma unroll
    for (int ni=0;ni<2;++ni){
      int c2 = c0 + ni*16 + ln16;
      int d = c2>>4, hh = (c2>>1)&7;
#pragma unroll
      for (int r=0;r<4;++r){
        int m = m0blk + mw0 + mi*16 + g*4 + r;
        int bq = (m>=2352)?3:(m>=1568)?2:(m>=784)?1:0;
        int nk = m - bq*784;
        unsigned short val = f2b(acc[mi][ni][r]);
        if (c2&1){
          vT[(((size_t)bq*NH+hh)*HD + d)*NKVP + nk] = val;
        } else {
          int chunk = nk & ~31, pos = nk & 31;
          int gg = pos>>3, jj = pos&7;
          int row = (jj<4) ? (gg*4+jj) : (16 + gg*4 + (jj-4));
          kb[(((size_t)bq*NH+hh)*NKVP + chunk + row)*HD + d] = val;
        }
      }
    }
}

// ---- fused attention: 32 q-rows/wave, 3-buffer LDS pipeline, counted vmcnt.
// grid (32, 25) = (bh, 128-row tile). bh pins to XCD bh%8.
__global__ __launch_bounds__(256) void k_attn(const unsigned short* __restrict__ qb,
      const unsigned short* __restrict__ kb, const unsigned short* __restrict__ vT,
      const unsigned short* __restrict__ bias2, unsigned short* __restrict__ aout){
  __shared__ unsigned short kv0[2048], kv1[2048], kv2[2048];
  const int tid=threadIdx.x, wv=tid>>6, l=tid&63, g=l>>4, ln16=l&15;
  const int bh = blockIdx.x, b = bh>>3, h = bh&7;
  const int nq0 = blockIdx.y*128 + wv*16;
  const int nq1 = nq0 + 64;
  const bool act1 = (nq1 < NTOK);
  const int nq1c = act1 ? nq1 : nq0;
  const s16x8 qf0 = *(const s16x8*)&qb[((size_t)b*NTOK + nq0  + ln16)*CD + h*HD + g*8];
  const s16x8 qf1 = *(const s16x8*)&qb[((size_t)b*NTOK + nq1c + ln16)*CD + h*HD + g*8];
  const unsigned short* kbase = kb + (size_t)bh*NKVP*HD;
  const unsigned short* vbase = vT + (size_t)bh*HD*NKVP;
  const unsigned short* bp0 = bias2 + (size_t)(nq0  + ln16)*NKVP + g*8;
  const unsigned short* bp1 = bias2 + (size_t)(nq1c + ln16)*NKVP + g*8;
  const int lslot = ((l&3)^((l>>3)&3))*8;
  const unsigned short* sp = (wv < 2)
      ? (kbase + (size_t)(wv*16 + (l>>2))*HD + lslot)
      : (vbase + (size_t)((wv-2)*16 + (l>>2))*NKVP + lslot);
  const int sstep = (wv < 2) ? 1024 : 32;
  const int ko0 = ln16*32 + (g ^ ((ln16>>1)&3))*8;
  unsigned short *bA = kv0, *bB = kv1, *bC = kv2;
  f32x4 acc00={}, acc01={}, acc10={}, acc11={};
  float S0=0.f, S1=0.f;
  const f32x4 zf = {};
  gload16(sp, bA + wv*512);
  u16x8 bb0 = *(const u16x8*)bp0;
  u16x8 bb1 = *(const u16x8*)bp1;
  gload16(sp + sstep, bB + wv*512);
  u16x8 c0v = *(const u16x8*)(bp0 + 32);
  u16x8 c1v = *(const u16x8*)(bp1 + 32);
  for (int it=0; it<25; ++it){
    if (it < 23) asm volatile("s_waitcnt vmcnt(3)" ::: "memory");
    else         asm volatile("s_waitcnt vmcnt(0)" ::: "memory");
    __builtin_amdgcn_s_barrier();
    __builtin_amdgcn_sched_barrier(0);
    u16x8 n0v = c0v, n1v = c1v;
    if (it < 23){
      gload16(sp + (it+2)*sstep, bC + wv*512);
      n0v = *(const u16x8*)(bp0 + (it+2)*32);
      n1v = *(const u16x8*)(bp1 + (it+2)*32);
    }
    s16x8 ka0 = *(const s16x8*)&bA[ko0];
    s16x8 ka1 = *(const s16x8*)&bA[512 + ko0];
    s16x8 v0  = *(const s16x8*)&bA[1024 + ko0];
    s16x8 v1  = *(const s16x8*)&bA[1536 + ko0];
    __builtin_amdgcn_s_setprio(1);
    f32x4 d00 = MFMA16(ka0, qf0, zf);
    f32x4 d10 = MFMA16(ka1, qf0, zf);
    f32x4 d01 = MFMA16(ka0, qf1, zf);
    f32x4 d11 = MFMA16(ka1, qf1, zf);
    float p0[8], p1[8];
#pragma unroll
    for (int r=0;r<4;++r){
      p0[r]   = exp2f(d00[r] + b2f(bb0[r]));
      p0[4+r] = exp2f(d10[r] + b2f(bb0[4+r]));
      p1[r]   = exp2f(d01[r] + b2f(bb1[r]));
      p1[4+r] = exp2f(d11[r] + b2f(bb1[4+r]));
    }
    S0 += ((p0[0]+p0[1])+(p0[2]+p0[3])) + ((p0[4]+p0[5])+(p0[6]+p0[7]));
    S1 += ((p1[0]+p1[1])+(p1[2]+p1[3])) + ((p1[4]+p1[5])+(p1[6]+p1[7]));
    s16x8 pf0 = pack8(p0);
    s16x8 pf1 = pack8(p1);
    acc00 = MFMA16(pf0, v0, acc00);
    acc01 = MFMA16(pf0, v1, acc01);
    acc10 = MFMA16(pf1, v0, acc10);
    acc11 = MFMA16(pf1, v1, acc11);
    __builtin_amdgcn_s_setprio(0);
    unsigned short* tmp = bA; bA = bB; bB = bC; bC = tmp;
    bb0 = c0v; c0v = n0v;
    bb1 = c1v; c1v = n1v;
  }
  S0 += __shfl_xor(S0, 16); S0 += __shfl_xor(S0, 32);
  S1 += __shfl_xor(S1, 16); S1 += __shfl_xor(S1, 32);
#pragma unroll
  for (int r=0;r<4;++r){
    float inv = 1.f / __shfl(S0, g*4 + r);
    int n = nq0 + g*4 + r;
    aout[((size_t)b*NTOK + n)*CD + h*HD + ln16]      = f2b(acc00[r]*inv);
    aout[((size_t)b*NTOK + n)*CD + h*HD + 16 + ln16] = f2b(acc01[r]*inv);
  }
  if (act1){
#pragma unroll
    for (int r=0;r<4;++r){
      float inv = 1.f / __shfl(S1, g*4 + r);
      int n = nq1 + g*4 + r;
      aout[((size_t)b*NTOK + n)*CD + h*HD + ln16]      = f2b(acc10[r]*inv);
      aout[((size_t)b*NTOK + n)*CD + h*HD + 16 + ln16] = f2b(acc11[r]*inv);
    }
  }
}

// ---- out projection: A=pwT rows c, B=aout rows n, pipelined. grid (196,4)
__global__ __launch_bounds__(256) void k_proj(const unsigned short* __restrict__ ain,
      const unsigned short* __restrict__ pwT, const float* __restrict__ pb,
      float* __restrict__ out){
  const int tid=threadIdx.x, wv=tid>>6, l=tid&63, g=l>>4, ln16=l&15;
  const int bI = blockIdx.x/49;
  const int n0 = (blockIdx.x%49)*64;
  const int nsub = n0 + (wv&1)*32;
  const int c0 = blockIdx.y*64 + (wv>>1)*32;
  const unsigned short* ap0 = &pwT[(size_t)(c0+ln16)*CD + g*8];
  const unsigned short* ap1 = ap0 + 16*CD;
  const unsigned short* bp0 = &ain[((size_t)bI*NTOK + nsub+ln16)*CD + g*8];
  const unsigned short* bp1 = bp0 + 16*CD;
  f32x4 acc[2][2] = {};   // [mi over c][ni over n]
  s16x8 a0 = *(const s16x8*)ap0, a1 = *(const s16x8*)ap1;
  s16x8 w0 = *(const s16x8*)bp0, w1 = *(const s16x8*)bp1;
#pragma unroll
  for (int k0=0; k0<CD; k0+=32){
    s16x8 na0 = *(const s16x8*)(ap0 + k0+32);
    s16x8 na1 = *(const s16x8*)(ap1 + k0+32);
    s16x8 nw0 = *(const s16x8*)(bp0 + k0+32);
    s16x8 nw1 = *(const s16x8*)(bp1 + k0+32);
    acc[0][0] = MFMA16(a0, w0, acc[0][0]);
    acc[0][1] = MFMA16(a0, w1, acc[0][1]);
    acc[1][0] = MFMA16(a1, w0, acc[1][0]);
    acc[1][1] = MFMA16(a1, w1, acc[1][1]);
    a0=na0; a1=na1; w0=nw0; w1=nw1;
  }
#pragma unroll
  for (int mi=0;mi<2;++mi)
#pragma unroll
    for (int r=0;r<4;++r){
      int c = c0 + mi*16 + g*4 + r;
      float bias = pb[c];
#pragma unroll
      for (int ni=0;ni<2;++ni){
        int n = nsub + ni*16 + ln16;
        out[((size_t)bI*CD + c)*NTOK + n] = acc[mi][ni][r] + bias;
      }
    }
}

extern "C" void kernel_launch(void* const* d_in, const int* in_sizes, int n_in,
                              void* d_out, int out_size, void* d_ws, size_t ws_size,
                              hipStream_t stream){
  const float* x   = (const float*)d_in[0];
  const float* Wq  = (const float*)d_in[1];
  const float* Wkv = (const float*)d_in[2];
  const float* srw = (const float*)d_in[3];
  const float* srb = (const float*)d_in[4];
  const float* lng = (const float*)d_in[5];
  const float* lnb = (const float*)d_in[6];
  const float* pos = (const float*)d_in[7];
  const float* pw  = (const float*)d_in[8];
  const float* pb  = (const float*)d_in[9];
  float* out = (float*)d_out;

  unsigned char* p = (unsigned char*)d_ws;
  unsigned short* WqT   = (unsigned short*)(p + 0);         // 131072 B
  unsigned short* WkvT  = (unsigned short*)(p + 131072);    // 262144 B
  unsigned short* pwT   = (unsigned short*)(p + 393216);    // 131072 B
  unsigned short* srwb2 = (unsigned short*)(p + 524288);    // 524288 B
  unsigned short* bias2 = (unsigned short*)(p + 1048576);   // 5017600 B
  unsigned short* xbf   = (unsigned short*)(p + 6066176);   // 6422528 B
  unsigned short* qbuf  = (unsigned short*)(p + 12488704);  // 6422528 B
  float*          convo = (float*)        (p + 18911232);   // 3211264 B
  unsigned short* kbuf  = (unsigned short*)(p + 22122496);  // 1638400 B
  unsigned short* vT    = (unsigned short*)(p + 23760896);  // 1638400 B
  unsigned short* aout  = (unsigned short*)(p + 25399296);  // 6422528 B

  k_prep <<<5136, 256, 0, stream>>>(Wq, Wkv, pw, srw, pos, x,
                                    WqT, WkvT, pwT, srwb2, bias2, xbf, kbuf, vT);
  k_qc   <<<980, 256, 0, stream>>>(xbf, WqT, srwb2, srb, qbuf, convo);
  k_kvln <<<dim3(49,8), 256, 0, stream>>>(convo, lng, lnb, WkvT, kbuf, vT);
  k_attn <<<dim3(32,25), 256, 0, stream>>>(qbuf, kbuf, vT, bias2, aout);
  k_proj <<<dim3(196,4), 256, 0, stream>>>(aout, pwT, pb, out);
}